// Round 7
// baseline (115.307 us; speedup 1.0000x reference)
//
#include <hip/hip_runtime.h>

// SGAN_PoolingNet: pooled[i] = max_j relu( relu([hidden[j], (ends[j]-ends[i])@We+be] @ W1 + b1) @ W2 + b2 )
// Collapse: y_lin[i,j,:] = A[j,:] - U[i,:]
//   A[j,k] = hidden[j]@W1[0:64,k] + ends[j]@M2[:,k] + b1[k] + be@W1[64:80,k]   (f32 math, stored bf16)
//   U[i,k] = ends[i]@M2[:,k],  M2 = We @ W1[64:80,:]  (2x128, f32)
// pool_main: per block = TWO agents (i0,i1); Z = relu(A - U[i]) @ W2 via mfma_f32_16x16x32_bf16
// (mapping verified R3/R6: absmax 0.03125), row-max, +b2, relu.
// R7 changes (evidence: R6 falsified spill theory — VGPR 80 w/ (256,3) bound, occupancy still 24%,
// VALUBusy 52% = ~26us of VALU issue dominated by software-RNE pack):
//   (a) RTZ pack via v_perm_b32: 1 instr/pair replaces ~12-instr RNE sequence (y>=0, trunc <=1ulp);
//   (b) dual-agent blocks: A-load + unpack shared across 2 agents -> per-agent VALU ~halved,
//       A L2 traffic halved, 512 blocks = exactly 2/CU single-pass.

#define N_AG 1024

typedef __attribute__((ext_vector_type(8))) short short8;        // 8 bf16 = 4 VGPR (MFMA A/B frag)
typedef __attribute__((ext_vector_type(4))) float floatx4;       // MFMA C/D frag
typedef __attribute__((ext_vector_type(4))) unsigned int uintx4; // 4 packed bf16 pairs

__device__ __forceinline__ unsigned short f2bf(float f) {
  unsigned u = __builtin_bit_cast(unsigned, f);
  u += 0x7FFFu + ((u >> 16) & 1u);   // RNE (prep only)
  return (unsigned short)(u >> 16);
}

// pack two f32 -> bf16 pair by truncation (RTZ): one v_perm_b32
__device__ __forceinline__ unsigned pack2bf_rtz(float y0, float y1) {
  return __builtin_amdgcn_perm(__builtin_bit_cast(unsigned, y1),
                               __builtin_bit_cast(unsigned, y0), 0x07060302u);
}

// ---- prep (fused): block j computes A[j]; block 0 writes M2; blocks 0..31 write W2T ----
__global__ __launch_bounds__(128) void prep_all(
    const float* __restrict__ hidden,  // (1,1024,64)
    const float* __restrict__ track,   // (1024,8,2)
    const float* __restrict__ We,      // (2,16)
    const float* __restrict__ be,      // (16)
    const float* __restrict__ W1,      // (80,128)
    const float* __restrict__ b1,      // (128)
    const float* __restrict__ W2,      // (128,64)
    unsigned short* __restrict__ Abf,  // (1024,128) bf16
    float* __restrict__ M2f,           // (2,128) f32
    unsigned short* __restrict__ W2T)  // (64,128) bf16, transposed
{
  int j = blockIdx.x;
  int k = threadIdx.x;   // 0..127
  __shared__ float hj[64];
  if (k < 64) hj[k] = hidden[j * 64 + k];
  __syncthreads();
  float e0 = track[j * 16 + 14];
  float e1 = track[j * 16 + 15];
  float m20 = 0.f, m21 = 0.f, cb = b1[k];
#pragma unroll
  for (int t = 0; t < 16; ++t) {
    float w1v = W1[(64 + t) * 128 + k];
    m20 += We[t] * w1v;
    m21 += We[16 + t] * w1v;
    cb  += be[t] * w1v;
  }
  float acc = e0 * m20 + e1 * m21 + cb;
#pragma unroll 16
  for (int t = 0; t < 64; ++t) acc += hj[t] * W1[t * 128 + k];
  Abf[j * 128 + k] = f2bf(acc);

  if (j == 0) {           // m20/m21 are exactly M2[0][k], M2[1][k]
    M2f[k]       = m20;
    M2f[128 + k] = m21;
  }
  if (j < 32) {           // W2T[n][c] = bf16(W2[c][n]); 32 blocks x 256 entries
#pragma unroll
    for (int q = 0; q < 2; ++q) {
      int idx = j * 256 + q * 128 + k;
      int n = idx >> 7, c = idx & 127;
      W2T[n * 128 + c] = f2bf(W2[c * 64 + n]);
    }
  }
}

// ---- main: one block per agent PAIR, 4 waves split 64 j-tiles ----
__global__ __launch_bounds__(256) void pool_main(
    const unsigned short* __restrict__ Abf,   // (1024,128) bf16
    const float* __restrict__ M2f,            // (2,128) f32
    const float* __restrict__ track,          // (1024,8,2) f32
    const unsigned short* __restrict__ W2T,   // (64,128) bf16
    const float* __restrict__ b2,             // (64) f32
    float* __restrict__ out)                  // (1024,64) f32
{
  const int i0   = blockIdx.x * 2;
  const int lane = threadIdx.x & 63;
  const int wave = threadIdx.x >> 6;
  const int m    = lane & 15;   // A row within tile / B-and-D column
  const int quad = lane >> 4;   // k-subrange selector

  // U for both agents, f32, the 32 k's this lane touches
  const float a_e0 = track[i0 * 16 + 14],       a_e1 = track[i0 * 16 + 15];
  const float b_e0 = track[(i0 + 1) * 16 + 14], b_e1 = track[(i0 + 1) * 16 + 15];
  float u0[4][8], u1[4][8];
#pragma unroll
  for (int kk = 0; kk < 4; ++kk) {
#pragma unroll
    for (int jj = 0; jj < 8; ++jj) {
      int kidx = kk * 32 + quad * 8 + jj;
      float m2a = M2f[kidx], m2b = M2f[128 + kidx];
      u0[kk][jj] = a_e0 * m2a + a_e1 * m2b;
      u1[kk][jj] = b_e0 * m2a + b_e1 * m2b;
    }
  }

  // B fragments resident in registers (shared by both agents)
  short8 bfrag[4][4];
#pragma unroll
  for (int t = 0; t < 4; ++t)
#pragma unroll
    for (int kk = 0; kk < 4; ++kk)
      bfrag[t][kk] = *(const short8*)(W2T + (t * 16 + m) * 128 + kk * 32 + quad * 8);

  floatx4 mx0[4], mx1[4];
#pragma unroll
  for (int t = 0; t < 4; ++t) {
    mx0[t] = (floatx4){-3e38f, -3e38f, -3e38f, -3e38f};
    mx1[t] = (floatx4){-3e38f, -3e38f, -3e38f, -3e38f};
  }

  const unsigned short* Aptr = Abf + (wave * 16 + m) * 128 + quad * 8;
#pragma unroll 2
  for (int it = 0; it < 16; ++it, Aptr += 4 * 16 * 128) {
    uintx4 au0[4], au1[4];
#pragma unroll
    for (int kk = 0; kk < 4; ++kk) {
      uintx4 raw = *(const uintx4*)(Aptr + kk * 32);
#pragma unroll
      for (int p = 0; p < 4; ++p) {
        unsigned w = raw[p];
        float lo = __builtin_bit_cast(float, w << 16);          // element 2p   (low half)
        float hi = __builtin_bit_cast(float, w & 0xFFFF0000u);  // element 2p+1 (high half)
        float y0a = fmaxf(lo - u0[kk][2 * p], 0.f);
        float y1a = fmaxf(hi - u0[kk][2 * p + 1], 0.f);
        float y0b = fmaxf(lo - u1[kk][2 * p], 0.f);
        float y1b = fmaxf(hi - u1[kk][2 * p + 1], 0.f);
        au0[kk][p] = pack2bf_rtz(y0a, y1a);
        au1[kk][p] = pack2bf_rtz(y0b, y1b);
      }
    }
#pragma unroll
    for (int t = 0; t < 4; ++t) {
      floatx4 acc0 = (floatx4){0.f, 0.f, 0.f, 0.f};
      floatx4 acc1 = (floatx4){0.f, 0.f, 0.f, 0.f};
#pragma unroll
      for (int kk = 0; kk < 4; ++kk) {
        acc0 = __builtin_amdgcn_mfma_f32_16x16x32_bf16(
            __builtin_bit_cast(short8, au0[kk]), bfrag[t][kk], acc0, 0, 0, 0);
        acc1 = __builtin_amdgcn_mfma_f32_16x16x32_bf16(
            __builtin_bit_cast(short8, au1[kk]), bfrag[t][kk], acc1, 0, 0, 0);
      }
#pragma unroll
      for (int r = 0; r < 4; ++r) {
        mx0[t][r] = fmaxf(mx0[t][r], acc0[r]);
        mx1[t][r] = fmaxf(mx1[t][r], acc1[r]);
      }
    }
  }

  // D layout: row = quad*4 + r (j-dim), col = m. In-lane then cross-quad; cross-wave via LDS.
  float lm0[4], lm1[4];
#pragma unroll
  for (int t = 0; t < 4; ++t) {
    lm0[t] = fmaxf(fmaxf(mx0[t][0], mx0[t][1]), fmaxf(mx0[t][2], mx0[t][3]));
    lm0[t] = fmaxf(lm0[t], __shfl_xor(lm0[t], 16, 64));
    lm0[t] = fmaxf(lm0[t], __shfl_xor(lm0[t], 32, 64));
    lm1[t] = fmaxf(fmaxf(mx1[t][0], mx1[t][1]), fmaxf(mx1[t][2], mx1[t][3]));
    lm1[t] = fmaxf(lm1[t], __shfl_xor(lm1[t], 16, 64));
    lm1[t] = fmaxf(lm1[t], __shfl_xor(lm1[t], 32, 64));
  }
  __shared__ float red[4][2][64];
  if (quad == 0) {
#pragma unroll
    for (int t = 0; t < 4; ++t) {
      red[wave][0][t * 16 + m] = lm0[t];
      red[wave][1][t * 16 + m] = lm1[t];
    }
  }
  __syncthreads();
  if (threadIdx.x < 128) {
    int a = threadIdx.x >> 6;   // agent select
    int n = threadIdx.x & 63;   // output channel
    float v = fmaxf(fmaxf(red[0][a][n], red[1][a][n]),
                    fmaxf(red[2][a][n], red[3][a][n]));
    v += b2[n];
    v = v > 0.f ? v : 0.f;
    out[(i0 + a) * 64 + n] = v;
  }
}

extern "C" void kernel_launch(void* const* d_in, const int* in_sizes, int n_in,
                              void* d_out, int out_size, void* d_ws, size_t ws_size,
                              hipStream_t stream) {
  const float* hidden = (const float*)d_in[0]; // (1,1024,64)
  const float* track  = (const float*)d_in[1]; // (1024,8,2)
  const float* We     = (const float*)d_in[2]; // (2,16)
  const float* be     = (const float*)d_in[3]; // (16)
  const float* W1     = (const float*)d_in[4]; // (80,128)
  const float* b1     = (const float*)d_in[5]; // (128)
  const float* W2     = (const float*)d_in[6]; // (128,64)
  const float* b2     = (const float*)d_in[7]; // (64)
  float* out = (float*)d_out;

  char* ws = (char*)d_ws;
  unsigned short* Abf = (unsigned short*)ws;              // 1024*128*2 = 256 KiB
  float*          M2f = (float*)(ws + 262144);            // 256*4     = 1 KiB
  unsigned short* W2T = (unsigned short*)(ws + 263168);   // 64*128*2  = 16 KiB

  prep_all<<<N_AG, 128, 0, stream>>>(hidden, track, We, be, W1, b1, W2, Abf, M2f, W2T);
  pool_main<<<N_AG / 2, 256, 0, stream>>>(Abf, M2f, track, W2T, b2, out);
}